// Round 1
// baseline (801.968 us; speedup 1.0000x reference)
//
#include <hip/hip_runtime.h>

// AugmentedNeuralODE: B=16384 independent 2-D ODEs (aug dims are identically 0),
// 7 intervals x 2 dopri5 substeps x 6 stages = 84 evals of [x,y,t]->128->128->2 MLP.
// Compute-bound fp32: 4.7e10 FLOP, roofline ~300us on the 157 TF vector ALU.
//
// Parallelization: 8 waves cooperate on 64 samples (1 sample per lane).
// Each wave owns a 16-wide slice of the hidden dim:
//   layer1: wave computes h1[slice] for its lane's sample -> LDS h1T[i][sample]
//   layer2: wave computes h2[slice] over all 128 i; weight index is wave-uniform
//           (readfirstlane) so W2 reads become s_load on the scalar pipe
//   layer3: per-wave partial v -> LDS -> 8-way add
// 2 barriers per eval. State + k1..k6 live in registers.

#define HID 128
#define NW  8            // waves per block
#define CH  (HID/NW)     // hidden units per wave = 16
#define BS  64           // samples per block = lanes per wave
#define TT  8            // time points

#define F(a,b) ((float)((double)(a)/(double)(b)))

__device__ __forceinline__ float tanh_fast(float x) {
  // tanh(x) = 1 - 2/(exp(2x)+1); exp->inf/0 gives exact +-1 saturation.
  float e = __expf(x + x);
  float r = __builtin_amdgcn_rcpf(e + 1.0f);
  return fmaf(-2.0f, r, 1.0f);
}

__global__ __launch_bounds__(NW * 64, 2) void node_kernel(
    const float* __restrict__ r0, const float* __restrict__ tarr,
    const float* __restrict__ W1, const float* __restrict__ b1,
    const float* __restrict__ W2, const float* __restrict__ b2,
    const float* __restrict__ W3, const float* __restrict__ b3,
    float* __restrict__ out)
{
  __shared__ float h1T[HID * BS];      // 32 KB, [i][sample]: lane-contiguous
  __shared__ float vpart[NW * 2 * BS]; // 4 KB per-wave partial velocities

  const int lane = (int)(threadIdx.x & 63u);
  // Force wave id scalar so W2/b2/W3 indices are provably wave-uniform -> s_load.
  const int wq = __builtin_amdgcn_readfirstlane((int)(threadIdx.x >> 6));
  const int c0 = wq * CH;
  const int s  = (int)blockIdx.x * BS + lane;

  float x = r0[2 * s + 0];
  float y = r0[2 * s + 1];
  if (wq == 0) { out[(s * TT + 0) * 2 + 0] = x; out[(s * TT + 0) * 2 + 1] = y; }

  auto feval = [&](float tt, float sx, float sy, float& vx, float& vy) {
    // ---- layer 1 (rows 0,1,4 of W1; aug inputs are 0) ----
    #pragma unroll
    for (int ii = 0; ii < CH; ++ii) {
      int i = c0 + ii;
      float a = b1[i];
      a = fmaf(sx, W1[0 * HID + i], a);
      a = fmaf(sy, W1[1 * HID + i], a);
      a = fmaf(tt, W1[4 * HID + i], a);
      h1T[i * BS + lane] = tanh_fast(a);
    }
    __syncthreads();
    // ---- layer 2: this wave's 16 outputs over all 128 inputs ----
    float acc[CH];
    #pragma unroll
    for (int jj = 0; jj < CH; ++jj) acc[jj] = b2[c0 + jj];
    #pragma unroll 4
    for (int i = 0; i < HID; ++i) {
      float hv = h1T[i * BS + lane];
      const float* wrow = W2 + i * HID + c0;   // wave-uniform -> s_load_dwordx16
      #pragma unroll
      for (int jj = 0; jj < CH; ++jj) acc[jj] = fmaf(hv, wrow[jj], acc[jj]);
    }
    // ---- tanh + layer 3 partial ----
    float px = 0.f, py = 0.f;
    #pragma unroll
    for (int jj = 0; jj < CH; ++jj) {
      float h2 = tanh_fast(acc[jj]);
      px = fmaf(h2, W3[(c0 + jj) * 2 + 0], px);
      py = fmaf(h2, W3[(c0 + jj) * 2 + 1], py);
    }
    vpart[(wq * 2 + 0) * BS + lane] = px;
    vpart[(wq * 2 + 1) * BS + lane] = py;
    __syncthreads();
    float rx = b3[0], ry = b3[1];
    #pragma unroll
    for (int w = 0; w < NW; ++w) {
      rx += vpart[(w * 2 + 0) * BS + lane];
      ry += vpart[(w * 2 + 1) * BS + lane];
    }
    vx = rx; vy = ry;
  };

  #pragma unroll 1
  for (int iv = 0; iv < TT - 1; ++iv) {
    float t0 = tarr[iv], t1 = tarr[iv + 1];
    float dt = (t1 - t0) * 0.5f;
    #pragma unroll 1
    for (int ss = 0; ss < 2; ++ss) {
      float tb = (ss == 0) ? t0 : (t0 + dt);
      float k1x,k1y,k2x,k2y,k3x,k3y,k4x,k4y,k5x,k5y,k6x,k6y;
      float xa, ya;
      feval(tb, x, y, k1x, k1y);
      { float c = dt * F(1,5);
        feval(tb + dt * F(1,5), fmaf(c,k1x,x), fmaf(c,k1y,y), k2x, k2y); }
      xa = fmaf(dt, fmaf(F(3,40),k1x, F(9,40)*k2x), x);
      ya = fmaf(dt, fmaf(F(3,40),k1y, F(9,40)*k2y), y);
      feval(tb + dt * F(3,10), xa, ya, k3x, k3y);
      xa = fmaf(dt, fmaf(F(44,45),k1x, fmaf(-F(56,15),k2x, F(32,9)*k3x)), x);
      ya = fmaf(dt, fmaf(F(44,45),k1y, fmaf(-F(56,15),k2y, F(32,9)*k3y)), y);
      feval(tb + dt * F(4,5), xa, ya, k4x, k4y);
      xa = fmaf(dt, fmaf(F(19372,6561),k1x, fmaf(-F(25360,2187),k2x,
               fmaf(F(64448,6561),k3x, -F(212,729)*k4x))), x);
      ya = fmaf(dt, fmaf(F(19372,6561),k1y, fmaf(-F(25360,2187),k2y,
               fmaf(F(64448,6561),k3y, -F(212,729)*k4y))), y);
      feval(tb + dt * F(8,9), xa, ya, k5x, k5y);
      xa = fmaf(dt, fmaf(F(9017,3168),k1x, fmaf(-F(355,33),k2x,
               fmaf(F(46732,5247),k3x, fmaf(F(49,176),k4x,
               -F(5103,18656)*k5x)))), x);
      ya = fmaf(dt, fmaf(F(9017,3168),k1y, fmaf(-F(355,33),k2y,
               fmaf(F(46732,5247),k3y, fmaf(F(49,176),k4y,
               -F(5103,18656)*k5y)))), y);
      feval(tb + dt, xa, ya, k6x, k6y);
      x = fmaf(dt, fmaf(F(35,384),k1x, fmaf(F(500,1113),k3x,
              fmaf(F(125,192),k4x, fmaf(-F(2187,6784),k5x, F(11,84)*k6x)))), x);
      y = fmaf(dt, fmaf(F(35,384),k1y, fmaf(F(500,1113),k3y,
              fmaf(F(125,192),k4y, fmaf(-F(2187,6784),k5y, F(11,84)*k6y)))), y);
    }
    if (wq == 0) {
      out[(s * TT + iv + 1) * 2 + 0] = x;
      out[(s * TT + iv + 1) * 2 + 1] = y;
    }
  }
}

extern "C" void kernel_launch(void* const* d_in, const int* in_sizes, int n_in,
                              void* d_out, int out_size, void* d_ws, size_t ws_size,
                              hipStream_t stream) {
  const float* r0 = (const float*)d_in[0];
  const float* t  = (const float*)d_in[1];
  const float* W1 = (const float*)d_in[2];
  const float* b1 = (const float*)d_in[3];
  const float* W2 = (const float*)d_in[4];
  const float* b2 = (const float*)d_in[5];
  const float* W3 = (const float*)d_in[6];
  const float* b3 = (const float*)d_in[7];
  float* out = (float*)d_out;
  const int B = in_sizes[0] / 2;          // 16384
  dim3 grid(B / BS), block(NW * 64);      // 256 blocks x 512 threads
  node_kernel<<<grid, block, 0, stream>>>(r0, t, W1, b1, W2, b2, W3, b3, out);
}

// Round 2
// 235.415 us; speedup vs baseline: 3.4066x; 3.4066x over previous
//
#include <hip/hip_runtime.h>

// AugmentedNeuralODE, round 2: MFMA for the 128x128 layer.
// 512 blocks x 256 threads (4 waves, 2 blocks/CU). 32 samples/block, each
// sample's RK state replicated on 8 lanes (r = tid>>5). Per eval:
//   layer1 (fp32 VALU, 16 units/lane) -> tanh -> bf16 pack -> LDS in exact
//   B-fragment order ([kgroup][sample][8k], 16B units);
//   layer2 = 32x mfma_f32_16x16x32_bf16 per wave; W2 lives in VGPRs as
//   hi+lo split bf16 (A-fragments, preloaded once -> no W2 quant error);
//   h2 tanh + layer3 partials on C-layout regs; quad-reduce via shfl_xor,
//   wave-reduce via LDS. 2 barriers/eval, 168 evals.

#define HID 128
#define NS  32           // samples per block
#define NWAVE 4
#define TT  8
#define F(a,b) ((float)((double)(a)/(double)(b)))

typedef __attribute__((ext_vector_type(8))) short bf16x8;
typedef __attribute__((ext_vector_type(4))) float f32x4;

union Frag { bf16x8 v; unsigned short u[8]; unsigned int d[4]; };

__device__ __forceinline__ unsigned short f2bf(float f) {
  unsigned u = __builtin_bit_cast(unsigned, f);
  u += 0x7FFFu + ((u >> 16) & 1u);          // RNE
  return (unsigned short)(u >> 16);
}
__device__ __forceinline__ float bf2f(unsigned short h) {
  unsigned u = ((unsigned)h) << 16;
  return __builtin_bit_cast(float, u);
}
__device__ __forceinline__ float tanh_fast(float x) {
  // tanh(x) = 1 - 2/(exp(2x)+1); saturates exactly at +-1.
  float e = __expf(x + x);
  float r = __builtin_amdgcn_rcpf(e + 1.0f);
  return fmaf(-2.0f, r, 1.0f);
}

__global__ __launch_bounds__(256, 2) void node_kernel(
    const float* __restrict__ r0, const float* __restrict__ tarr,
    const float* __restrict__ W1, const float* __restrict__ b1,
    const float* __restrict__ W2, const float* __restrict__ b2,
    const float* __restrict__ W3, const float* __restrict__ b3,
    float* __restrict__ out)
{
  __shared__ uint4  h1L[16 * NS];      // [kgroup][n], 16B = 8 bf16 each; 8 KB
  __shared__ float2 vrS[NWAVE * NS];   // per-wave partial velocities; 1 KB

  const int tid  = (int)threadIdx.x;
  const int lane = tid & 63;
  const int w    = tid >> 6;           // wave 0..3
  const int quad = lane >> 4;          // 0..3
  const int m16  = lane & 15;
  const int n    = tid & 31;           // my sample slot in block
  const int r    = tid >> 5;           // replica / unit-group seed 0..7
  const int s    = (int)blockIdx.x * NS + n;

  // ---- one-time preloads (all unrolled -> registers) ----
  // layer-1 weights for unit groups g = r and r+8 (units i = g*8+j)
  float w1x[2][8], w1y[2][8], w1t[2][8], bb1[2][8];
  #pragma unroll
  for (int gi = 0; gi < 2; ++gi) {
    int g = r + 8 * gi;
    #pragma unroll
    for (int j = 0; j < 8; ++j) {
      int i = g * 8 + j;
      w1x[gi][j] = W1[0 * HID + i];
      w1y[gi][j] = W1[1 * HID + i];
      w1t[gi][j] = W1[4 * HID + i];
      bb1[gi][j] = b1[i];
    }
  }
  // W2 A-fragments, hi/lo bf16 split. A[m][k] = W2[k][o], o = ot*16+m16,
  // k = kk*32 + quad*8 + j. Wave w owns out-tiles 2w, 2w+1.
  Frag Ah[2][4], Al[2][4];
  #pragma unroll
  for (int oti = 0; oti < 2; ++oti) {
    int o = (2 * w + oti) * 16 + m16;
    #pragma unroll
    for (int kk = 0; kk < 4; ++kk) {
      #pragma unroll
      for (int j = 0; j < 8; ++j) {
        float val = W2[(kk * 32 + quad * 8 + j) * HID + o];
        unsigned short hi = f2bf(val);
        unsigned short lo = f2bf(val - bf2f(hi));
        Ah[oti][kk].u[j] = hi;
        Al[oti][kk].u[j] = lo;
      }
    }
  }
  // b2 / W3 for the C-layout rows this lane holds: o = ot*16 + quad*4 + rr
  float b2v[2][4], w3x[2][4], w3y[2][4];
  #pragma unroll
  for (int oti = 0; oti < 2; ++oti) {
    #pragma unroll
    for (int rr = 0; rr < 4; ++rr) {
      int o = (2 * w + oti) * 16 + quad * 4 + rr;
      b2v[oti][rr] = b2[o];
      w3x[oti][rr] = W3[o * 2 + 0];
      w3y[oti][rr] = W3[o * 2 + 1];
    }
  }
  const float b3x = b3[0], b3y = b3[1];

  float x = r0[2 * s + 0];
  float y = r0[2 * s + 1];
  if (tid < 32) { out[(s * TT + 0) * 2 + 0] = x; out[(s * TT + 0) * 2 + 1] = y; }

  auto feval = [&](float tt, float sx, float sy, float& vx, float& vy) {
    // ---- layer 1: 16 units for my sample, bf16-packed into B-frag order ----
    #pragma unroll
    for (int gi = 0; gi < 2; ++gi) {
      Frag hf;
      #pragma unroll
      for (int j = 0; j < 8; ++j) {
        float a = bb1[gi][j];
        a = fmaf(sx, w1x[gi][j], a);
        a = fmaf(sy, w1y[gi][j], a);
        a = fmaf(tt, w1t[gi][j], a);
        hf.u[j] = f2bf(tanh_fast(a));
      }
      int g = r + 8 * gi;
      h1L[g * NS + n] = make_uint4(hf.d[0], hf.d[1], hf.d[2], hf.d[3]);
    }
    __syncthreads();
    // ---- layer 2: MFMA. acc[oti][nt] over K=128 in 4 steps, hi+lo ----
    f32x4 acc[2][2];
    #pragma unroll
    for (int oti = 0; oti < 2; ++oti)
      #pragma unroll
      for (int nt = 0; nt < 2; ++nt)
        acc[oti][nt] = f32x4{0.f, 0.f, 0.f, 0.f};
    #pragma unroll
    for (int nt = 0; nt < 2; ++nt) {
      #pragma unroll
      for (int kk = 0; kk < 4; ++kk) {
        Frag bfr;
        uint4 t4 = h1L[(kk * 4 + quad) * NS + nt * 16 + m16];
        bfr.d[0] = t4.x; bfr.d[1] = t4.y; bfr.d[2] = t4.z; bfr.d[3] = t4.w;
        #pragma unroll
        for (int oti = 0; oti < 2; ++oti) {
          acc[oti][nt] = __builtin_amdgcn_mfma_f32_16x16x32_bf16(
              Ah[oti][kk].v, bfr.v, acc[oti][nt], 0, 0, 0);
          acc[oti][nt] = __builtin_amdgcn_mfma_f32_16x16x32_bf16(
              Al[oti][kk].v, bfr.v, acc[oti][nt], 0, 0, 0);
        }
      }
    }
    // ---- h2 tanh + layer-3 partials (C-layout: row=quad*4+rr, col=m16) ----
    float px[2] = {0.f, 0.f}, py[2] = {0.f, 0.f};
    #pragma unroll
    for (int nt = 0; nt < 2; ++nt) {
      #pragma unroll
      for (int oti = 0; oti < 2; ++oti) {
        #pragma unroll
        for (int rr = 0; rr < 4; ++rr) {
          float h2 = tanh_fast(acc[oti][nt][rr] + b2v[oti][rr]);
          px[nt] = fmaf(h2, w3x[oti][rr], px[nt]);
          py[nt] = fmaf(h2, w3y[oti][rr], py[nt]);
        }
      }
    }
    // reduce over the 4 quads (same sample column) in-register
    #pragma unroll
    for (int nt = 0; nt < 2; ++nt) {
      px[nt] += __shfl_xor(px[nt], 16); px[nt] += __shfl_xor(px[nt], 32);
      py[nt] += __shfl_xor(py[nt], 16); py[nt] += __shfl_xor(py[nt], 32);
    }
    if (lane < 32) {                       // lanes 0-15: nt=0, 16-31: nt=1
      int nt = lane >> 4;
      vrS[w * NS + nt * 16 + m16] = make_float2(px[nt], py[nt]);
    }
    __syncthreads();
    float rx = b3x, ry = b3y;
    #pragma unroll
    for (int ww = 0; ww < NWAVE; ++ww) {
      float2 p = vrS[ww * NS + n];
      rx += p.x; ry += p.y;
    }
    vx = rx; vy = ry;
  };

  #pragma unroll 1
  for (int iv = 0; iv < TT - 1; ++iv) {
    float t0 = tarr[iv], t1 = tarr[iv + 1];
    float dt = (t1 - t0) * 0.5f;
    #pragma unroll 1
    for (int ss = 0; ss < 2; ++ss) {
      float tb = (ss == 0) ? t0 : (t0 + dt);
      float k1x,k1y,k2x,k2y,k3x,k3y,k4x,k4y,k5x,k5y,k6x,k6y;
      float xa, ya;
      feval(tb, x, y, k1x, k1y);
      { float c = dt * F(1,5);
        feval(tb + dt * F(1,5), fmaf(c,k1x,x), fmaf(c,k1y,y), k2x, k2y); }
      xa = fmaf(dt, fmaf(F(3,40),k1x, F(9,40)*k2x), x);
      ya = fmaf(dt, fmaf(F(3,40),k1y, F(9,40)*k2y), y);
      feval(tb + dt * F(3,10), xa, ya, k3x, k3y);
      xa = fmaf(dt, fmaf(F(44,45),k1x, fmaf(-F(56,15),k2x, F(32,9)*k3x)), x);
      ya = fmaf(dt, fmaf(F(44,45),k1y, fmaf(-F(56,15),k2y, F(32,9)*k3y)), y);
      feval(tb + dt * F(4,5), xa, ya, k4x, k4y);
      xa = fmaf(dt, fmaf(F(19372,6561),k1x, fmaf(-F(25360,2187),k2x,
               fmaf(F(64448,6561),k3x, -F(212,729)*k4x))), x);
      ya = fmaf(dt, fmaf(F(19372,6561),k1y, fmaf(-F(25360,2187),k2y,
               fmaf(F(64448,6561),k3y, -F(212,729)*k4y))), y);
      feval(tb + dt * F(8,9), xa, ya, k5x, k5y);
      xa = fmaf(dt, fmaf(F(9017,3168),k1x, fmaf(-F(355,33),k2x,
               fmaf(F(46732,5247),k3x, fmaf(F(49,176),k4x,
               -F(5103,18656)*k5x)))), x);
      ya = fmaf(dt, fmaf(F(9017,3168),k1y, fmaf(-F(355,33),k2y,
               fmaf(F(46732,5247),k3y, fmaf(F(49,176),k4y,
               -F(5103,18656)*k5y)))), y);
      feval(tb + dt, xa, ya, k6x, k6y);
      x = fmaf(dt, fmaf(F(35,384),k1x, fmaf(F(500,1113),k3x,
              fmaf(F(125,192),k4x, fmaf(-F(2187,6784),k5x, F(11,84)*k6x)))), x);
      y = fmaf(dt, fmaf(F(35,384),k1y, fmaf(F(500,1113),k3y,
              fmaf(F(125,192),k4y, fmaf(-F(2187,6784),k5y, F(11,84)*k6y)))), y);
    }
    if (tid < 32) {
      out[(s * TT + iv + 1) * 2 + 0] = x;
      out[(s * TT + iv + 1) * 2 + 1] = y;
    }
  }
}

extern "C" void kernel_launch(void* const* d_in, const int* in_sizes, int n_in,
                              void* d_out, int out_size, void* d_ws, size_t ws_size,
                              hipStream_t stream) {
  const float* r0 = (const float*)d_in[0];
  const float* t  = (const float*)d_in[1];
  const float* W1 = (const float*)d_in[2];
  const float* b1 = (const float*)d_in[3];
  const float* W2 = (const float*)d_in[4];
  const float* b2 = (const float*)d_in[5];
  const float* W3 = (const float*)d_in[6];
  const float* b3 = (const float*)d_in[7];
  float* out = (float*)d_out;
  const int B = in_sizes[0] / 2;            // 16384
  dim3 grid(B / NS), block(NWAVE * 64);     // 512 blocks x 256 threads
  node_kernel<<<grid, block, 0, stream>>>(r0, t, W1, b1, W2, b2, W3, b3, out);
}

// Round 3
// 215.463 us; speedup vs baseline: 3.7221x; 1.0926x over previous
//
#include <hip/hip_runtime.h>

// AugmentedNeuralODE, round 3: occupancy restructure.
// 1024 blocks x 256 threads (4 waves), NS=16 samples/block, 4 blocks/CU
// (launch_bounds(256,4), VGPR<=128). Each sample replicated on 16 lanes
// (r = tid>>4); per lane: 8 layer-1 units + 8 h2-tanh -> half the per-lane
// work of round 2, twice the waves. W2 held in registers as bf16 (hi only;
// lo-correction dropped to fit 4 waves/SIMD -> half the MFMAs too).
//   layer1 (fp32) -> tanh -> v_perm bf16 pack -> LDS in B-frag order;
//   layer2 = 8x mfma_f32_16x16x32_bf16 per wave (2 out-tiles x 4 K-slabs);
//   epilogue tanh + W3 partials on C-layout regs; quad-reduce shfl_xor,
//   4-wave reduce via LDS. 2 barriers/eval, 168 evals.

#define HID 128
#define NS  16           // samples per block
#define NWAVE 4
#define TT  8
#define F(a,b) ((float)((double)(a)/(double)(b)))

typedef __attribute__((ext_vector_type(8))) short bf16x8;
typedef __attribute__((ext_vector_type(4))) float f32x4;

union Frag { bf16x8 v; unsigned short u[8]; unsigned int d[4]; };

__device__ __forceinline__ unsigned short f2bf(float f) {
  unsigned u = __builtin_bit_cast(unsigned, f);
  u += 0x7FFFu + ((u >> 16) & 1u);          // RNE
  return (unsigned short)(u >> 16);
}
__device__ __forceinline__ unsigned pack2bf(float a, float b) {
  // dword = (bf16(b)<<16) | bf16(a), RNE, via v_perm_b32
  unsigned ua = __builtin_bit_cast(unsigned, a);
  unsigned ub = __builtin_bit_cast(unsigned, b);
  ua += 0x7FFFu + ((ua >> 16) & 1u);
  ub += 0x7FFFu + ((ub >> 16) & 1u);
  return __builtin_amdgcn_perm(ub, ua, 0x07060302u);
}
__device__ __forceinline__ float tanh_fast(float x) {
  // tanh(x) = 1 - 2/(exp(2x)+1); saturates exactly at +-1.
  float e = __expf(x + x);
  float r = __builtin_amdgcn_rcpf(e + 1.0f);
  return fmaf(-2.0f, r, 1.0f);
}

__global__ __launch_bounds__(256, 4) void node_kernel(
    const float* __restrict__ r0, const float* __restrict__ tarr,
    const float* __restrict__ W1, const float* __restrict__ b1,
    const float* __restrict__ W2, const float* __restrict__ b2,
    const float* __restrict__ W3, const float* __restrict__ b3,
    float* __restrict__ out)
{
  __shared__ uint4  h1L[16 * NS];      // [kgroup][n], 16B = 8 bf16; 4 KB
  __shared__ float2 vrS[NWAVE * NS];   // per-wave partial velocities; 512 B

  const int tid  = (int)threadIdx.x;
  const int lane = tid & 63;
  const int w    = __builtin_amdgcn_readfirstlane(tid >> 6); // wave 0..3
  const int quad = lane >> 4;          // 0..3
  const int m16  = lane & 15;
  const int n    = tid & 15;           // my sample slot in block
  const int r    = tid >> 4;           // unit-group 0..15 (8 units each)
  const int s    = (int)blockIdx.x * NS + n;

  // ---- one-time preloads (unrolled -> registers) ----
  // layer-1 weights for units i = r*8 + j
  float w1x[8], w1y[8], w1t[8], bb1[8];
  #pragma unroll
  for (int j = 0; j < 8; ++j) {
    int i = r * 8 + j;
    w1x[j] = W1[0 * HID + i];
    w1y[j] = W1[1 * HID + i];
    w1t[j] = W1[4 * HID + i];
    bb1[j] = b1[i];
  }
  // W2 A-fragments (bf16 hi only). A[m][k] = W2[k][o], o = tile*16+m16,
  // k = kk*32 + quad*8 + j. Wave w owns out-tiles 2w, 2w+1.
  Frag Ah[2][4];
  #pragma unroll
  for (int oti = 0; oti < 2; ++oti) {
    int o = (2 * w + oti) * 16 + m16;
    #pragma unroll
    for (int kk = 0; kk < 4; ++kk)
      #pragma unroll
      for (int j = 0; j < 8; ++j)
        Ah[oti][kk].u[j] = f2bf(W2[(kk * 32 + quad * 8 + j) * HID + o]);
  }
  // b2 / W3 for C-layout rows: o = tile*16 + quad*4 + rr
  float b2v[2][4], w3x[2][4], w3y[2][4];
  #pragma unroll
  for (int oti = 0; oti < 2; ++oti)
    #pragma unroll
    for (int rr = 0; rr < 4; ++rr) {
      int o = (2 * w + oti) * 16 + quad * 4 + rr;
      b2v[oti][rr] = b2[o];
      w3x[oti][rr] = W3[o * 2 + 0];
      w3y[oti][rr] = W3[o * 2 + 1];
    }
  const float b3x = b3[0], b3y = b3[1];

  float x = r0[2 * s + 0];
  float y = r0[2 * s + 1];
  if (tid < NS) { out[(s * TT + 0) * 2 + 0] = x; out[(s * TT + 0) * 2 + 1] = y; }

  auto feval = [&](float tt, float sx, float sy, float& vx, float& vy) {
    // ---- layer 1: 8 units for my sample -> bf16 pack -> B-frag slot ----
    {
      float h[8];
      #pragma unroll
      for (int j = 0; j < 8; ++j) {
        float a = bb1[j];
        a = fmaf(sx, w1x[j], a);
        a = fmaf(sy, w1y[j], a);
        a = fmaf(tt, w1t[j], a);
        h[j] = tanh_fast(a);
      }
      uint4 pk;
      pk.x = pack2bf(h[0], h[1]); pk.y = pack2bf(h[2], h[3]);
      pk.z = pack2bf(h[4], h[5]); pk.w = pack2bf(h[6], h[7]);
      h1L[r * NS + n] = pk;
    }
    __syncthreads();
    // ---- layer 2: MFMA over K=128 in 4 slabs, 2 out-tiles ----
    f32x4 acc[2];
    acc[0] = f32x4{0.f, 0.f, 0.f, 0.f};
    acc[1] = f32x4{0.f, 0.f, 0.f, 0.f};
    #pragma unroll
    for (int kk = 0; kk < 4; ++kk) {
      Frag bfr;
      uint4 t4 = h1L[(kk * 4 + quad) * NS + m16];
      bfr.d[0] = t4.x; bfr.d[1] = t4.y; bfr.d[2] = t4.z; bfr.d[3] = t4.w;
      acc[0] = __builtin_amdgcn_mfma_f32_16x16x32_bf16(Ah[0][kk].v, bfr.v, acc[0], 0, 0, 0);
      acc[1] = __builtin_amdgcn_mfma_f32_16x16x32_bf16(Ah[1][kk].v, bfr.v, acc[1], 0, 0, 0);
    }
    // ---- h2 tanh + layer-3 partials (C-layout: row=quad*4+rr, col=m16) ----
    float px = 0.f, py = 0.f;
    #pragma unroll
    for (int oti = 0; oti < 2; ++oti)
      #pragma unroll
      for (int rr = 0; rr < 4; ++rr) {
        float h2 = tanh_fast(acc[oti][rr] + b2v[oti][rr]);
        px = fmaf(h2, w3x[oti][rr], px);
        py = fmaf(h2, w3y[oti][rr], py);
      }
    // reduce over the 4 quads (same sample column) in-register
    px += __shfl_xor(px, 16); px += __shfl_xor(px, 32);
    py += __shfl_xor(py, 16); py += __shfl_xor(py, 32);
    if (lane < 16) vrS[w * NS + m16] = make_float2(px, py);
    __syncthreads();
    float rx = b3x, ry = b3y;
    #pragma unroll
    for (int ww = 0; ww < NWAVE; ++ww) {
      float2 p = vrS[ww * NS + n];
      rx += p.x; ry += p.y;
    }
    vx = rx; vy = ry;
  };

  #pragma unroll 1
  for (int iv = 0; iv < TT - 1; ++iv) {
    float t0 = tarr[iv], t1 = tarr[iv + 1];
    float dt = (t1 - t0) * 0.5f;
    #pragma unroll 1
    for (int ss = 0; ss < 2; ++ss) {
      float tb = (ss == 0) ? t0 : (t0 + dt);
      float k1x,k1y,k2x,k2y,k3x,k3y,k4x,k4y,k5x,k5y,k6x,k6y;
      float xa, ya;
      feval(tb, x, y, k1x, k1y);
      { float c = dt * F(1,5);
        feval(tb + dt * F(1,5), fmaf(c,k1x,x), fmaf(c,k1y,y), k2x, k2y); }
      xa = fmaf(dt, fmaf(F(3,40),k1x, F(9,40)*k2x), x);
      ya = fmaf(dt, fmaf(F(3,40),k1y, F(9,40)*k2y), y);
      feval(tb + dt * F(3,10), xa, ya, k3x, k3y);
      xa = fmaf(dt, fmaf(F(44,45),k1x, fmaf(-F(56,15),k2x, F(32,9)*k3x)), x);
      ya = fmaf(dt, fmaf(F(44,45),k1y, fmaf(-F(56,15),k2y, F(32,9)*k3y)), y);
      feval(tb + dt * F(4,5), xa, ya, k4x, k4y);
      xa = fmaf(dt, fmaf(F(19372,6561),k1x, fmaf(-F(25360,2187),k2x,
               fmaf(F(64448,6561),k3x, -F(212,729)*k4x))), x);
      ya = fmaf(dt, fmaf(F(19372,6561),k1y, fmaf(-F(25360,2187),k2y,
               fmaf(F(64448,6561),k3y, -F(212,729)*k4y))), y);
      feval(tb + dt * F(8,9), xa, ya, k5x, k5y);
      xa = fmaf(dt, fmaf(F(9017,3168),k1x, fmaf(-F(355,33),k2x,
               fmaf(F(46732,5247),k3x, fmaf(F(49,176),k4x,
               -F(5103,18656)*k5x)))), x);
      ya = fmaf(dt, fmaf(F(9017,3168),k1y, fmaf(-F(355,33),k2y,
               fmaf(F(46732,5247),k3y, fmaf(F(49,176),k4y,
               -F(5103,18656)*k5y)))), y);
      feval(tb + dt, xa, ya, k6x, k6y);
      x = fmaf(dt, fmaf(F(35,384),k1x, fmaf(F(500,1113),k3x,
              fmaf(F(125,192),k4x, fmaf(-F(2187,6784),k5x, F(11,84)*k6x)))), x);
      y = fmaf(dt, fmaf(F(35,384),k1y, fmaf(F(500,1113),k3y,
              fmaf(F(125,192),k4y, fmaf(-F(2187,6784),k5y, F(11,84)*k6y)))), y);
    }
    if (tid < NS) {
      out[(s * TT + iv + 1) * 2 + 0] = x;
      out[(s * TT + iv + 1) * 2 + 1] = y;
    }
  }
}

extern "C" void kernel_launch(void* const* d_in, const int* in_sizes, int n_in,
                              void* d_out, int out_size, void* d_ws, size_t ws_size,
                              hipStream_t stream) {
  const float* r0 = (const float*)d_in[0];
  const float* t  = (const float*)d_in[1];
  const float* W1 = (const float*)d_in[2];
  const float* b1 = (const float*)d_in[3];
  const float* W2 = (const float*)d_in[4];
  const float* b2 = (const float*)d_in[5];
  const float* W3 = (const float*)d_in[6];
  const float* b3 = (const float*)d_in[7];
  float* out = (float*)d_out;
  const int B = in_sizes[0] / 2;            // 16384
  dim3 grid(B / NS), block(NWAVE * 64);     // 1024 blocks x 256 threads
  node_kernel<<<grid, block, 0, stream>>>(r0, t, W1, b1, W2, b2, W3, b3, out);
}

// Round 4
// 203.846 us; speedup vs baseline: 3.9342x; 1.0570x over previous
//
#include <hip/hip_runtime.h>

// AugmentedNeuralODE, round 4: packed-fp32 issue-width optimization.
// Same structure as round 3 (1024 blocks x 256 thr, NS=16, 16 lanes/sample,
// W2-in-regs bf16 A-frags, 8x mfma 16x16x32_bf16 per eval, 2 barriers/eval).
// All full-rate fp32 chains are rewritten as float2 ext-vectors so the
// backend emits v_pk_{fma,mul,add}_f32: layer-1 unit pairs, tanh wrappers,
// h2+b2, W3 partials (px,py packed), RK state algebra (x,y packed), final
// reduce. Transcendental count unchanged (16 tanh = 32 trans per lane-eval).

#define HID 128
#define NS  16           // samples per block
#define NWAVE 4
#define TT  8
#define F(a,b) ((float)((double)(a)/(double)(b)))

typedef __attribute__((ext_vector_type(8))) short bf16x8;
typedef __attribute__((ext_vector_type(4))) float f32x4;
typedef __attribute__((ext_vector_type(2))) float f32x2;

union Frag { bf16x8 v; unsigned short u[8]; unsigned int d[4]; };

__device__ __forceinline__ f32x2 bc(float s) { return f32x2{s, s}; }
__device__ __forceinline__ f32x2 pk_fma(f32x2 a, f32x2 b, f32x2 c) {
#if __has_builtin(__builtin_elementwise_fma)
  return __builtin_elementwise_fma(a, b, c);
#else
  return a * b + c;   // hipcc default -ffp-contract=fast
#endif
}
__device__ __forceinline__ float exp2_fast(float x) {
#if __has_builtin(__builtin_amdgcn_exp2f)
  return __builtin_amdgcn_exp2f(x);
#else
  return __builtin_exp2f(x);
#endif
}

__device__ __forceinline__ unsigned short f2bf(float f) {
  unsigned u = __builtin_bit_cast(unsigned, f);
  u += 0x7FFFu + ((u >> 16) & 1u);          // RNE
  return (unsigned short)(u >> 16);
}
__device__ __forceinline__ unsigned pack2bf(float a, float b) {
  // dword = (bf16(b)<<16) | bf16(a), RNE, via v_perm_b32
  unsigned ua = __builtin_bit_cast(unsigned, a);
  unsigned ub = __builtin_bit_cast(unsigned, b);
  ua += 0x7FFFu + ((ua >> 16) & 1u);
  ub += 0x7FFFu + ((ub >> 16) & 1u);
  return __builtin_amdgcn_perm(ub, ua, 0x07060302u);
}

// tanh on a pair: 3 pk ops + 2 exp + 2 rcp. tanh(x) = 1 - 2/(exp2(x*2log2e)+1).
__device__ __forceinline__ f32x2 tanh_pk(f32x2 x) {
  const float K2 = 2.8853900817779268f;    // 2*log2(e)
  f32x2 u = x * bc(K2);                    // v_pk_mul_f32
  f32x2 e;
  e.x = exp2_fast(u.x);
  e.y = exp2_fast(u.y);
  f32x2 d = e + bc(1.0f);                  // v_pk_add_f32
  f32x2 r;
  r.x = __builtin_amdgcn_rcpf(d.x);
  r.y = __builtin_amdgcn_rcpf(d.y);
  return pk_fma(bc(-2.0f), r, bc(1.0f));   // v_pk_fma_f32
}

__global__ __launch_bounds__(256, 4) void node_kernel(
    const float* __restrict__ r0, const float* __restrict__ tarr,
    const float* __restrict__ W1, const float* __restrict__ b1,
    const float* __restrict__ W2, const float* __restrict__ b2,
    const float* __restrict__ W3, const float* __restrict__ b3,
    float* __restrict__ out)
{
  __shared__ uint4  h1L[16 * NS];      // [kgroup][n], 16B = 8 bf16; 4 KB
  __shared__ float2 vrS[NWAVE * NS];   // per-wave partial velocities; 512 B

  const int tid  = (int)threadIdx.x;
  const int lane = tid & 63;
  const int w    = __builtin_amdgcn_readfirstlane(tid >> 6); // wave 0..3
  const int quad = lane >> 4;          // 0..3
  const int m16  = lane & 15;
  const int n    = tid & 15;           // my sample slot in block
  const int r    = tid >> 4;           // unit-group 0..15 (8 units each)
  const int s    = (int)blockIdx.x * NS + n;

  // ---- one-time preloads (unrolled -> registers) ----
  // layer-1 weights for units i = r*8 + j, as pairs (2p, 2p+1)
  f32x2 w1x[4], w1y[4], w1t[4], bb1[4];
  #pragma unroll
  for (int p = 0; p < 4; ++p) {
    int i = r * 8 + 2 * p;
    w1x[p] = f32x2{W1[0 * HID + i], W1[0 * HID + i + 1]};
    w1y[p] = f32x2{W1[1 * HID + i], W1[1 * HID + i + 1]};
    w1t[p] = f32x2{W1[4 * HID + i], W1[4 * HID + i + 1]};
    bb1[p] = f32x2{b1[i], b1[i + 1]};
  }
  // W2 A-fragments (bf16). A[m][k] = W2[k][o], o = tile*16+m16,
  // k = kk*32 + quad*8 + j. Wave w owns out-tiles 2w, 2w+1.
  Frag Ah[2][4];
  #pragma unroll
  for (int oti = 0; oti < 2; ++oti) {
    int o = (2 * w + oti) * 16 + m16;
    #pragma unroll
    for (int kk = 0; kk < 4; ++kk)
      #pragma unroll
      for (int j = 0; j < 8; ++j)
        Ah[oti][kk].u[j] = f2bf(W2[(kk * 32 + quad * 8 + j) * HID + o]);
  }
  // b2 (pairs) / W3 ({x,y} per unit) for C-layout rows: o = tile*16+quad*4+rr
  f32x2 b2p[2][2], w3xy[2][4];
  #pragma unroll
  for (int oti = 0; oti < 2; ++oti) {
    #pragma unroll
    for (int p = 0; p < 2; ++p) {
      int o = (2 * w + oti) * 16 + quad * 4 + 2 * p;
      b2p[oti][p] = f32x2{b2[o], b2[o + 1]};
    }
    #pragma unroll
    for (int rr = 0; rr < 4; ++rr) {
      int o = (2 * w + oti) * 16 + quad * 4 + rr;
      w3xy[oti][rr] = f32x2{W3[o * 2 + 0], W3[o * 2 + 1]};
    }
  }
  const f32x2 b3v = f32x2{b3[0], b3[1]};

  f32x2 S = f32x2{r0[2 * s + 0], r0[2 * s + 1]};
  if (tid < NS) *(float2*)&out[(s * TT + 0) * 2] = make_float2(S.x, S.y);

  auto feval = [&](float tt, f32x2 st) -> f32x2 {
    const f32x2 sx = bc(st.x), sy = bc(st.y), tv = bc(tt);
    // ---- layer 1: 8 units (4 pairs) -> tanh -> bf16 pack -> B-frag slot ----
    {
      uint4 pk;
      unsigned pd[4];
      #pragma unroll
      for (int p = 0; p < 4; ++p) {
        f32x2 a = pk_fma(sx, w1x[p], bb1[p]);
        a = pk_fma(sy, w1y[p], a);
        a = pk_fma(tv, w1t[p], a);
        f32x2 h = tanh_pk(a);
        pd[p] = pack2bf(h.x, h.y);
      }
      pk.x = pd[0]; pk.y = pd[1]; pk.z = pd[2]; pk.w = pd[3];
      h1L[r * NS + n] = pk;
    }
    __syncthreads();
    // ---- layer 2: MFMA over K=128 in 4 slabs, 2 out-tiles ----
    f32x4 acc[2];
    acc[0] = f32x4{0.f, 0.f, 0.f, 0.f};
    acc[1] = f32x4{0.f, 0.f, 0.f, 0.f};
    #pragma unroll
    for (int kk = 0; kk < 4; ++kk) {
      Frag bfr;
      uint4 t4 = h1L[(kk * 4 + quad) * NS + m16];
      bfr.d[0] = t4.x; bfr.d[1] = t4.y; bfr.d[2] = t4.z; bfr.d[3] = t4.w;
      acc[0] = __builtin_amdgcn_mfma_f32_16x16x32_bf16(Ah[0][kk].v, bfr.v, acc[0], 0, 0, 0);
      acc[1] = __builtin_amdgcn_mfma_f32_16x16x32_bf16(Ah[1][kk].v, bfr.v, acc[1], 0, 0, 0);
    }
    // ---- h2 tanh + layer-3 partials, packed (vsum = {px,py}) ----
    f32x2 vsum = bc(0.f);
    #pragma unroll
    for (int oti = 0; oti < 2; ++oti) {
      #pragma unroll
      for (int p = 0; p < 2; ++p) {
        f32x2 av = f32x2{acc[oti][2 * p], acc[oti][2 * p + 1]} + b2p[oti][p];
        f32x2 h2 = tanh_pk(av);
        vsum = pk_fma(bc(h2.x), w3xy[oti][2 * p + 0], vsum);
        vsum = pk_fma(bc(h2.y), w3xy[oti][2 * p + 1], vsum);
      }
    }
    // reduce over the 4 quads (same sample column) in-register
    float px = vsum.x, py = vsum.y;
    px += __shfl_xor(px, 16); px += __shfl_xor(px, 32);
    py += __shfl_xor(py, 16); py += __shfl_xor(py, 32);
    if (lane < 16) vrS[w * NS + m16] = make_float2(px, py);
    __syncthreads();
    f32x2 rv = b3v;
    #pragma unroll
    for (int ww = 0; ww < NWAVE; ++ww) {
      float2 pp = vrS[ww * NS + n];
      rv += f32x2{pp.x, pp.y};
    }
    return rv;
  };

  #pragma unroll 1
  for (int iv = 0; iv < TT - 1; ++iv) {
    float t0 = tarr[iv], t1 = tarr[iv + 1];
    float dt = (t1 - t0) * 0.5f;
    #pragma unroll 1
    for (int ss = 0; ss < 2; ++ss) {
      float tb = (ss == 0) ? t0 : (t0 + dt);
      const f32x2 dtv = bc(dt);
      f32x2 k1 = feval(tb, S);
      f32x2 k2 = feval(tb + dt * F(1,5), pk_fma(bc(dt * F(1,5)), k1, S));
      f32x2 a3 = pk_fma(bc(F(9,40)), k2, bc(F(3,40)) * k1);
      f32x2 k3 = feval(tb + dt * F(3,10), pk_fma(dtv, a3, S));
      f32x2 a4 = pk_fma(bc(F(44,45)), k1,
                 pk_fma(bc(-F(56,15)), k2, bc(F(32,9)) * k3));
      f32x2 k4 = feval(tb + dt * F(4,5), pk_fma(dtv, a4, S));
      f32x2 a5 = pk_fma(bc(F(19372,6561)), k1,
                 pk_fma(bc(-F(25360,2187)), k2,
                 pk_fma(bc(F(64448,6561)), k3, bc(-F(212,729)) * k4)));
      f32x2 k5 = feval(tb + dt * F(8,9), pk_fma(dtv, a5, S));
      f32x2 a6 = pk_fma(bc(F(9017,3168)), k1,
                 pk_fma(bc(-F(355,33)), k2,
                 pk_fma(bc(F(46732,5247)), k3,
                 pk_fma(bc(F(49,176)), k4, bc(-F(5103,18656)) * k5))));
      f32x2 k6 = feval(tb + dt, pk_fma(dtv, a6, S));
      f32x2 fin = pk_fma(bc(F(35,384)), k1,
                  pk_fma(bc(F(500,1113)), k3,
                  pk_fma(bc(F(125,192)), k4,
                  pk_fma(bc(-F(2187,6784)), k5, bc(F(11,84)) * k6))));
      S = pk_fma(dtv, fin, S);
    }
    if (tid < NS) *(float2*)&out[(s * TT + iv + 1) * 2] = make_float2(S.x, S.y);
  }
}

extern "C" void kernel_launch(void* const* d_in, const int* in_sizes, int n_in,
                              void* d_out, int out_size, void* d_ws, size_t ws_size,
                              hipStream_t stream) {
  const float* r0 = (const float*)d_in[0];
  const float* t  = (const float*)d_in[1];
  const float* W1 = (const float*)d_in[2];
  const float* b1 = (const float*)d_in[3];
  const float* W2 = (const float*)d_in[4];
  const float* b2 = (const float*)d_in[5];
  const float* W3 = (const float*)d_in[6];
  const float* b3 = (const float*)d_in[7];
  float* out = (float*)d_out;
  const int B = in_sizes[0] / 2;            // 16384
  dim3 grid(B / NS), block(NWAVE * 64);     // 1024 blocks x 256 threads
  node_kernel<<<grid, block, 0, stream>>>(r0, t, W1, b1, W2, b2, W3, b3, out);
}

// Round 5
// 199.214 us; speedup vs baseline: 4.0257x; 1.0233x over previous
//
#include <hip/hip_runtime.h>

// AugmentedNeuralODE, round 5: dual-stream pipelining.
// 512 blocks x 256 threads, NS=32 = two independent 16-sample groups (A,B)
// per block, 2 blocks/CU. Per eval: L1(A);L1(B); bar; MFMA(A);MFMA(B);
// epi(A) overlapping in-flight MFMA(B); epi(B); bar; RK(A,B).
// -> barriers per sample-eval halved, 2 indep streams per wave hide MFMA +
// ds_read latency. 2*log2(e) folded into W1/b1/W2/b2 so tanh needs no
// pre-scale mul (exp2 directly). W2 in regs as bf16 A-frags (2 out-tiles
// per wave), 16x mfma_f32_16x16x32_bf16 per wave-eval.

#define HID 128
#define NSG 16           // samples per group
#define NWAVE 4
#define TT  8
#define F(a,b) ((float)((double)(a)/(double)(b)))

typedef __attribute__((ext_vector_type(8))) short bf16x8;
typedef __attribute__((ext_vector_type(4))) float f32x4;
typedef __attribute__((ext_vector_type(2))) float f32x2;

union Frag { bf16x8 v; unsigned short u[8]; unsigned int d[4]; };

__device__ __forceinline__ f32x2 bc(float s) { return f32x2{s, s}; }
__device__ __forceinline__ f32x2 pk_fma(f32x2 a, f32x2 b, f32x2 c) {
#if __has_builtin(__builtin_elementwise_fma)
  return __builtin_elementwise_fma(a, b, c);
#else
  return a * b + c;
#endif
}
__device__ __forceinline__ float exp2_fast(float x) {
#if __has_builtin(__builtin_amdgcn_exp2f)
  return __builtin_amdgcn_exp2f(x);
#else
  return __builtin_exp2f(x);
#endif
}
__device__ __forceinline__ unsigned short f2bf(float f) {
  unsigned u = __builtin_bit_cast(unsigned, f);
  u += 0x7FFFu + ((u >> 16) & 1u);          // RNE
  return (unsigned short)(u >> 16);
}
__device__ __forceinline__ unsigned pack2bf(float a, float b) {
  unsigned ua = __builtin_bit_cast(unsigned, a);
  unsigned ub = __builtin_bit_cast(unsigned, b);
  ua += 0x7FFFu + ((ua >> 16) & 1u);
  ub += 0x7FFFu + ((ub >> 16) & 1u);
  return __builtin_amdgcn_perm(ub, ua, 0x07060302u);
}
// u is pre-scaled by 2*log2(e): tanh(x) = 1 - 2/(exp2(u)+1).
__device__ __forceinline__ f32x2 tanh_pre(f32x2 u) {
  f32x2 e;
  e.x = exp2_fast(u.x);
  e.y = exp2_fast(u.y);
  f32x2 d = e + bc(1.0f);
  f32x2 r;
  r.x = __builtin_amdgcn_rcpf(d.x);
  r.y = __builtin_amdgcn_rcpf(d.y);
  return pk_fma(bc(-2.0f), r, bc(1.0f));
}

#define K2C 2.8853900817779268f   // 2*log2(e)

__global__ __launch_bounds__(256, 2) void node_kernel(
    const float* __restrict__ r0, const float* __restrict__ tarr,
    const float* __restrict__ W1, const float* __restrict__ b1,
    const float* __restrict__ W2, const float* __restrict__ b2,
    const float* __restrict__ W3, const float* __restrict__ b3,
    float* __restrict__ out)
{
  __shared__ uint4  h1L[2][16 * NSG];     // per group: [kgroup][n]; 8 KB
  __shared__ float2 vrS[2][NWAVE * NSG];  // per group partial velocities; 1 KB

  const int tid  = (int)threadIdx.x;
  const int lane = tid & 63;
  const int w    = __builtin_amdgcn_readfirstlane(tid >> 6); // wave 0..3
  const int quad = lane >> 4;
  const int m16  = lane & 15;
  const int n    = tid & 15;            // sample slot within group
  const int r    = tid >> 4;            // unit-group 0..15 (8 units each)
  const int sA   = (int)blockIdx.x * (2 * NSG) + n;
  const int sB   = sA + NSG;

  // ---- one-time preloads (K2 folded into W1/b1/W2/b2) ----
  f32x2 w1x[4], w1y[4], w1t[4], bb1[4];
  #pragma unroll
  for (int p = 0; p < 4; ++p) {
    int i = r * 8 + 2 * p;
    w1x[p] = f32x2{W1[0 * HID + i], W1[0 * HID + i + 1]} * bc(K2C);
    w1y[p] = f32x2{W1[1 * HID + i], W1[1 * HID + i + 1]} * bc(K2C);
    w1t[p] = f32x2{W1[4 * HID + i], W1[4 * HID + i + 1]} * bc(K2C);
    bb1[p] = f32x2{b1[i], b1[i + 1]} * bc(K2C);
  }
  Frag Ah[2][4];
  #pragma unroll
  for (int oti = 0; oti < 2; ++oti) {
    int o = (2 * w + oti) * 16 + m16;
    #pragma unroll
    for (int kk = 0; kk < 4; ++kk)
      #pragma unroll
      for (int j = 0; j < 8; ++j)
        Ah[oti][kk].u[j] = f2bf(W2[(kk * 32 + quad * 8 + j) * HID + o] * K2C);
  }
  f32x2 b2p[2][2], w3xy[2][4];
  #pragma unroll
  for (int oti = 0; oti < 2; ++oti) {
    #pragma unroll
    for (int p = 0; p < 2; ++p) {
      int o = (2 * w + oti) * 16 + quad * 4 + 2 * p;
      b2p[oti][p] = f32x2{b2[o], b2[o + 1]} * bc(K2C);
    }
    #pragma unroll
    for (int rr = 0; rr < 4; ++rr) {
      int o = (2 * w + oti) * 16 + quad * 4 + rr;
      w3xy[oti][rr] = f32x2{W3[o * 2 + 0], W3[o * 2 + 1]};
    }
  }
  const f32x2 b3v = f32x2{b3[0], b3[1]};

  f32x2 SA = f32x2{r0[2 * sA + 0], r0[2 * sA + 1]};
  f32x2 SB = f32x2{r0[2 * sB + 0], r0[2 * sB + 1]};
  if (tid < 32) {
    int g = tid >> 4;
    int ss = (int)blockIdx.x * (2 * NSG) + tid;   // g*16 + n
    f32x2 S0 = g ? SB : SA;
    *(float2*)&out[(ss * TT + 0) * 2] = make_float2(S0.x, S0.y);
  }

  // one-group layer 1: compute 8 units, pack, store to this group's LDS
  auto layer1 = [&](int g, f32x2 st, float tt) {
    const f32x2 sx = bc(st.x), sy = bc(st.y), tv = bc(tt);
    unsigned pd[4];
    #pragma unroll
    for (int p = 0; p < 4; ++p) {
      f32x2 a = pk_fma(sx, w1x[p], bb1[p]);
      a = pk_fma(sy, w1y[p], a);
      a = pk_fma(tv, w1t[p], a);
      f32x2 h = tanh_pre(a);
      pd[p] = pack2bf(h.x, h.y);
    }
    h1L[g][r * NSG + n] = make_uint4(pd[0], pd[1], pd[2], pd[3]);
  };

  auto feval2 = [&](float tt, f32x2 stA, f32x2 stB, f32x2& vA, f32x2& vB) {
    layer1(0, stA, tt);
    layer1(1, stB, tt);
    __syncthreads();
    // ---- MFMA both groups back-to-back, then epilogues (overlap) ----
    Frag bfA[4], bfB[4];
    #pragma unroll
    for (int kk = 0; kk < 4; ++kk) {
      uint4 ta = h1L[0][(kk * 4 + quad) * NSG + m16];
      bfA[kk].d[0] = ta.x; bfA[kk].d[1] = ta.y; bfA[kk].d[2] = ta.z; bfA[kk].d[3] = ta.w;
      uint4 tb = h1L[1][(kk * 4 + quad) * NSG + m16];
      bfB[kk].d[0] = tb.x; bfB[kk].d[1] = tb.y; bfB[kk].d[2] = tb.z; bfB[kk].d[3] = tb.w;
    }
    f32x4 accA[2], accB[2];
    accA[0] = f32x4{0.f,0.f,0.f,0.f}; accA[1] = f32x4{0.f,0.f,0.f,0.f};
    accB[0] = f32x4{0.f,0.f,0.f,0.f}; accB[1] = f32x4{0.f,0.f,0.f,0.f};
    #pragma unroll
    for (int kk = 0; kk < 4; ++kk) {
      accA[0] = __builtin_amdgcn_mfma_f32_16x16x32_bf16(Ah[0][kk].v, bfA[kk].v, accA[0], 0, 0, 0);
      accA[1] = __builtin_amdgcn_mfma_f32_16x16x32_bf16(Ah[1][kk].v, bfA[kk].v, accA[1], 0, 0, 0);
    }
    #pragma unroll
    for (int kk = 0; kk < 4; ++kk) {
      accB[0] = __builtin_amdgcn_mfma_f32_16x16x32_bf16(Ah[0][kk].v, bfB[kk].v, accB[0], 0, 0, 0);
      accB[1] = __builtin_amdgcn_mfma_f32_16x16x32_bf16(Ah[1][kk].v, bfB[kk].v, accB[1], 0, 0, 0);
    }
    // epilogue A (accA ready; accB MFMAs still in flight behind it)
    f32x2 vsA = bc(0.f), vsB = bc(0.f);
    #pragma unroll
    for (int oti = 0; oti < 2; ++oti)
      #pragma unroll
      for (int p = 0; p < 2; ++p) {
        f32x2 av = f32x2{accA[oti][2*p], accA[oti][2*p+1]} + b2p[oti][p];
        f32x2 h2 = tanh_pre(av);
        vsA = pk_fma(bc(h2.x), w3xy[oti][2*p+0], vsA);
        vsA = pk_fma(bc(h2.y), w3xy[oti][2*p+1], vsA);
      }
    #pragma unroll
    for (int oti = 0; oti < 2; ++oti)
      #pragma unroll
      for (int p = 0; p < 2; ++p) {
        f32x2 av = f32x2{accB[oti][2*p], accB[oti][2*p+1]} + b2p[oti][p];
        f32x2 h2 = tanh_pre(av);
        vsB = pk_fma(bc(h2.x), w3xy[oti][2*p+0], vsB);
        vsB = pk_fma(bc(h2.y), w3xy[oti][2*p+1], vsB);
      }
    // quad reduction (cols = samples live in m16; reduce over lane>>4)
    float pxA = vsA.x, pyA = vsA.y, pxB = vsB.x, pyB = vsB.y;
    pxA += __shfl_xor(pxA, 16); pxA += __shfl_xor(pxA, 32);
    pyA += __shfl_xor(pyA, 16); pyA += __shfl_xor(pyA, 32);
    pxB += __shfl_xor(pxB, 16); pxB += __shfl_xor(pxB, 32);
    pyB += __shfl_xor(pyB, 16); pyB += __shfl_xor(pyB, 32);
    if (lane < 16) {
      vrS[0][w * NSG + m16] = make_float2(pxA, pyA);
      vrS[1][w * NSG + m16] = make_float2(pxB, pyB);
    }
    __syncthreads();
    f32x2 ra = b3v, rb = b3v;
    #pragma unroll
    for (int ww = 0; ww < NWAVE; ++ww) {
      float2 pa = vrS[0][ww * NSG + n];
      float2 pb = vrS[1][ww * NSG + n];
      ra += f32x2{pa.x, pa.y};
      rb += f32x2{pb.x, pb.y};
    }
    vA = ra; vB = rb;
  };

  #pragma unroll 1
  for (int iv = 0; iv < TT - 1; ++iv) {
    float t0 = tarr[iv], t1 = tarr[iv + 1];
    float dt = (t1 - t0) * 0.5f;
    #pragma unroll 1
    for (int ss = 0; ss < 2; ++ss) {
      float tb = (ss == 0) ? t0 : (t0 + dt);
      const f32x2 dtv = bc(dt);
      f32x2 k1A, k1B, k2A, k2B, k3A, k3B, k4A, k4B, k5A, k5B, k6A, k6B;
      feval2(tb, SA, SB, k1A, k1B);
      { f32x2 c = bc(dt * F(1,5));
        feval2(tb + dt * F(1,5), pk_fma(c, k1A, SA), pk_fma(c, k1B, SB), k2A, k2B); }
      {
        f32x2 aA = pk_fma(bc(F(9,40)), k2A, bc(F(3,40)) * k1A);
        f32x2 aB = pk_fma(bc(F(9,40)), k2B, bc(F(3,40)) * k1B);
        feval2(tb + dt * F(3,10), pk_fma(dtv, aA, SA), pk_fma(dtv, aB, SB), k3A, k3B);
      }
      {
        f32x2 aA = pk_fma(bc(F(44,45)), k1A, pk_fma(bc(-F(56,15)), k2A, bc(F(32,9)) * k3A));
        f32x2 aB = pk_fma(bc(F(44,45)), k1B, pk_fma(bc(-F(56,15)), k2B, bc(F(32,9)) * k3B));
        feval2(tb + dt * F(4,5), pk_fma(dtv, aA, SA), pk_fma(dtv, aB, SB), k4A, k4B);
      }
      {
        f32x2 aA = pk_fma(bc(F(19372,6561)), k1A, pk_fma(bc(-F(25360,2187)), k2A,
                   pk_fma(bc(F(64448,6561)), k3A, bc(-F(212,729)) * k4A)));
        f32x2 aB = pk_fma(bc(F(19372,6561)), k1B, pk_fma(bc(-F(25360,2187)), k2B,
                   pk_fma(bc(F(64448,6561)), k3B, bc(-F(212,729)) * k4B)));
        feval2(tb + dt * F(8,9), pk_fma(dtv, aA, SA), pk_fma(dtv, aB, SB), k5A, k5B);
      }
      {
        f32x2 aA = pk_fma(bc(F(9017,3168)), k1A, pk_fma(bc(-F(355,33)), k2A,
                   pk_fma(bc(F(46732,5247)), k3A, pk_fma(bc(F(49,176)), k4A,
                   bc(-F(5103,18656)) * k5A))));
        f32x2 aB = pk_fma(bc(F(9017,3168)), k1B, pk_fma(bc(-F(355,33)), k2B,
                   pk_fma(bc(F(46732,5247)), k3B, pk_fma(bc(F(49,176)), k4B,
                   bc(-F(5103,18656)) * k5B))));
        feval2(tb + dt, pk_fma(dtv, aA, SA), pk_fma(dtv, aB, SB), k6A, k6B);
      }
      {
        f32x2 fA = pk_fma(bc(F(35,384)), k1A, pk_fma(bc(F(500,1113)), k3A,
                   pk_fma(bc(F(125,192)), k4A, pk_fma(bc(-F(2187,6784)), k5A,
                   bc(F(11,84)) * k6A))));
        f32x2 fB = pk_fma(bc(F(35,384)), k1B, pk_fma(bc(F(500,1113)), k3B,
                   pk_fma(bc(F(125,192)), k4B, pk_fma(bc(-F(2187,6784)), k5B,
                   bc(F(11,84)) * k6B))));
        SA = pk_fma(dtv, fA, SA);
        SB = pk_fma(dtv, fB, SB);
      }
    }
    if (tid < 32) {
      int g = tid >> 4;
      int ss = (int)blockIdx.x * (2 * NSG) + tid;
      f32x2 Sg = g ? SB : SA;
      *(float2*)&out[(ss * TT + iv + 1) * 2] = make_float2(Sg.x, Sg.y);
    }
  }
}

extern "C" void kernel_launch(void* const* d_in, const int* in_sizes, int n_in,
                              void* d_out, int out_size, void* d_ws, size_t ws_size,
                              hipStream_t stream) {
  const float* r0 = (const float*)d_in[0];
  const float* t  = (const float*)d_in[1];
  const float* W1 = (const float*)d_in[2];
  const float* b1 = (const float*)d_in[3];
  const float* W2 = (const float*)d_in[4];
  const float* b2 = (const float*)d_in[5];
  const float* W3 = (const float*)d_in[6];
  const float* b3 = (const float*)d_in[7];
  float* out = (float*)d_out;
  const int B = in_sizes[0] / 2;               // 16384
  dim3 grid(B / (2 * NSG)), block(NWAVE * 64); // 512 blocks x 256 threads
  node_kernel<<<grid, block, 0, stream>>>(r0, t, W1, b1, W2, b2, W3, b3, out);
}

// Round 6
// 195.521 us; speedup vs baseline: 4.1017x; 1.0189x over previous
//
#include <hip/hip_runtime.h>

// AugmentedNeuralODE, round 6: LDS-free, barrier-free, wave-autonomous.
// Theory: R3-R5 were LDS-pipe-throughput-bound (~28 DS wave-ops/eval ~= wall).
// Fix: lane (quad,m16) computes h1 units k = kk*32+quad*8+j for sample m16 --
// that IS the MFMA B-fragment layout, so h1 never touches LDS. Each wave owns
// all 8 W2 out-tiles (full 128x128 layer for its 16 samples): no cross-wave
// exchange, no __syncthreads, no __shared__. 1024 blocks x 64 threads,
// 1 wave/SIMD, ~390 VGPR (launch_bounds(64,1) -> 512 budget).
// Per eval: 16 tanh-pairs L1 (in-lane B-frags) -> 32 MFMA (8 tiles x 4 K-slabs,
// acc init = b2) -> 16 tanh-pairs h2 + W3 partials -> 4 ds_bpermute quad-reduce
// -> RK (replicated x4 quads). Math identical to R5 (same tanh_pre, same bf16
// rounding, same K-order) -> absmax should repeat 0.03125.

#define HID 128
#define TT  8
#define F(a,b) ((float)((double)(a)/(double)(b)))
#define K2C 2.8853900817779268f   // 2*log2(e), folded into W1/b1/W2/b2

typedef __attribute__((ext_vector_type(8))) short bf16x8;
typedef __attribute__((ext_vector_type(4))) float f32x4;
typedef __attribute__((ext_vector_type(2))) float f32x2;

union Frag { bf16x8 v; unsigned short u[8]; unsigned int d[4]; };

__device__ __forceinline__ f32x2 bc(float s) { return f32x2{s, s}; }
__device__ __forceinline__ f32x2 pk_fma(f32x2 a, f32x2 b, f32x2 c) {
#if __has_builtin(__builtin_elementwise_fma)
  return __builtin_elementwise_fma(a, b, c);
#else
  return a * b + c;
#endif
}
__device__ __forceinline__ float exp2_fast(float x) {
#if __has_builtin(__builtin_amdgcn_exp2f)
  return __builtin_amdgcn_exp2f(x);
#else
  return __builtin_exp2f(x);
#endif
}
__device__ __forceinline__ unsigned short f2bf(float f) {
  unsigned u = __builtin_bit_cast(unsigned, f);
  u += 0x7FFFu + ((u >> 16) & 1u);          // RNE
  return (unsigned short)(u >> 16);
}
__device__ __forceinline__ unsigned pack2bf(float a, float b) {
  unsigned ua = __builtin_bit_cast(unsigned, a);
  unsigned ub = __builtin_bit_cast(unsigned, b);
  ua += 0x7FFFu + ((ua >> 16) & 1u);
  ub += 0x7FFFu + ((ub >> 16) & 1u);
  return __builtin_amdgcn_perm(ub, ua, 0x07060302u);
}
// u pre-scaled by 2*log2(e): tanh(x) = 1 - 2/(exp2(u)+1)
__device__ __forceinline__ f32x2 tanh_pre(f32x2 u) {
  f32x2 e;
  e.x = exp2_fast(u.x);
  e.y = exp2_fast(u.y);
  f32x2 d = e + bc(1.0f);
  f32x2 r;
  r.x = __builtin_amdgcn_rcpf(d.x);
  r.y = __builtin_amdgcn_rcpf(d.y);
  return pk_fma(bc(-2.0f), r, bc(1.0f));
}

__global__ __launch_bounds__(64, 1) void node_kernel(
    const float* __restrict__ r0, const float* __restrict__ tarr,
    const float* __restrict__ W1, const float* __restrict__ b1,
    const float* __restrict__ W2, const float* __restrict__ b2,
    const float* __restrict__ W3, const float* __restrict__ b3,
    float* __restrict__ out)
{
  const int lane = (int)(threadIdx.x & 63u);
  const int quad = lane >> 4;          // 0..3
  const int m16  = lane & 15;          // my sample (column)
  const int s    = (int)blockIdx.x * 16 + m16;

  // ---- one-time preloads, all K2-folded ----
  // W1 for my 32 units k = kk*32 + quad*8 + j, as 16 pairs (idx = kk*4+p)
  f32x2 w1x[16], w1y[16], w1t[16], bb1[16];
  #pragma unroll
  for (int kk = 0; kk < 4; ++kk)
    #pragma unroll
    for (int p = 0; p < 4; ++p) {
      int i = kk * 32 + quad * 8 + 2 * p;
      int idx = kk * 4 + p;
      w1x[idx] = f32x2{W1[0 * HID + i], W1[0 * HID + i + 1]} * bc(K2C);
      w1y[idx] = f32x2{W1[1 * HID + i], W1[1 * HID + i + 1]} * bc(K2C);
      w1t[idx] = f32x2{W1[4 * HID + i], W1[4 * HID + i + 1]} * bc(K2C);
      bb1[idx] = f32x2{b1[i], b1[i + 1]} * bc(K2C);
    }
  // W2 A-frags for ALL 8 out-tiles: A[m16][k=kk*32+quad*8+j] = W2[k][t*16+m16]
  Frag W2f[8][4];
  #pragma unroll
  for (int t = 0; t < 8; ++t) {
    int o = t * 16 + m16;
    #pragma unroll
    for (int kk = 0; kk < 4; ++kk)
      #pragma unroll
      for (int j = 0; j < 8; ++j)
        W2f[t][kk].u[j] = f2bf(W2[(kk * 32 + quad * 8 + j) * HID + o] * K2C);
  }
  // acc-init = b2 (K2-scaled); C rows this lane holds: o = t*16 + quad*4 + rr
  f32x4 b2i[8];
  f32x2 w3v[8][4];
  #pragma unroll
  for (int t = 0; t < 8; ++t)
    #pragma unroll
    for (int rr = 0; rr < 4; ++rr) {
      int o = t * 16 + quad * 4 + rr;
      b2i[t][rr] = b2[o] * K2C;
      w3v[t][rr] = f32x2{W3[o * 2 + 0], W3[o * 2 + 1]};
    }
  const f32x2 b3v = f32x2{b3[0], b3[1]};

  f32x2 S = f32x2{r0[2 * s + 0], r0[2 * s + 1]};
  if (lane < 16) *(float2*)&out[(s * TT + 0) * 2] = make_float2(S.x, S.y);

  auto feval = [&](float tt, f32x2 st) -> f32x2 {
    const f32x2 sx = bc(st.x), sy = bc(st.y), tv = bc(tt);
    // ---- layer 1: 32 units (16 pairs) -> bf16 B-frags, all in-lane ----
    unsigned hd[16];
    #pragma unroll
    for (int idx = 0; idx < 16; ++idx) {
      f32x2 a = pk_fma(sx, w1x[idx], bb1[idx]);
      a = pk_fma(sy, w1y[idx], a);
      a = pk_fma(tv, w1t[idx], a);
      f32x2 h = tanh_pre(a);
      hd[idx] = pack2bf(h.x, h.y);
    }
    // ---- layer 2: 32 MFMA (8 tiles x 4 K-slabs), acc pre-init with b2 ----
    f32x4 acc[8];
    #pragma unroll
    for (int t = 0; t < 8; ++t) acc[t] = b2i[t];
    #pragma unroll
    for (int kk = 0; kk < 4; ++kk) {
      Frag bv;
      bv.d[0] = hd[kk * 4 + 0]; bv.d[1] = hd[kk * 4 + 1];
      bv.d[2] = hd[kk * 4 + 2]; bv.d[3] = hd[kk * 4 + 3];
      #pragma unroll
      for (int t = 0; t < 8; ++t)
        acc[t] = __builtin_amdgcn_mfma_f32_16x16x32_bf16(W2f[t][kk].v, bv.v, acc[t], 0, 0, 0);
    }
    // ---- h2 tanh + layer-3 partials (C: row = quad*4+rr, col = m16) ----
    f32x2 vs = bc(0.f);
    #pragma unroll
    for (int t = 0; t < 8; ++t)
      #pragma unroll
      for (int p = 0; p < 2; ++p) {
        f32x2 av = f32x2{acc[t][2 * p], acc[t][2 * p + 1]};
        f32x2 h2 = tanh_pre(av);
        vs = pk_fma(bc(h2.x), w3v[t][2 * p + 0], vs);
        vs = pk_fma(bc(h2.y), w3v[t][2 * p + 1], vs);
      }
    // cross-quad reduce (sample m16 partials live at lanes m16+16q)
    float px = vs.x, py = vs.y;
    px += __shfl_xor(px, 16); px += __shfl_xor(px, 32);
    py += __shfl_xor(py, 16); py += __shfl_xor(py, 32);
    return f32x2{px, py} + b3v;
  };

  #pragma unroll 1
  for (int iv = 0; iv < TT - 1; ++iv) {
    float t0 = tarr[iv], t1 = tarr[iv + 1];
    float dt = (t1 - t0) * 0.5f;
    #pragma unroll 1
    for (int ss = 0; ss < 2; ++ss) {
      float tb = (ss == 0) ? t0 : (t0 + dt);
      const f32x2 dtv = bc(dt);
      f32x2 k1 = feval(tb, S);
      f32x2 k2 = feval(tb + dt * F(1,5), pk_fma(bc(dt * F(1,5)), k1, S));
      f32x2 a3 = pk_fma(bc(F(9,40)), k2, bc(F(3,40)) * k1);
      f32x2 k3 = feval(tb + dt * F(3,10), pk_fma(dtv, a3, S));
      f32x2 a4 = pk_fma(bc(F(44,45)), k1,
                 pk_fma(bc(-F(56,15)), k2, bc(F(32,9)) * k3));
      f32x2 k4 = feval(tb + dt * F(4,5), pk_fma(dtv, a4, S));
      f32x2 a5 = pk_fma(bc(F(19372,6561)), k1,
                 pk_fma(bc(-F(25360,2187)), k2,
                 pk_fma(bc(F(64448,6561)), k3, bc(-F(212,729)) * k4)));
      f32x2 k5 = feval(tb + dt * F(8,9), pk_fma(dtv, a5, S));
      f32x2 a6 = pk_fma(bc(F(9017,3168)), k1,
                 pk_fma(bc(-F(355,33)), k2,
                 pk_fma(bc(F(46732,5247)), k3,
                 pk_fma(bc(F(49,176)), k4, bc(-F(5103,18656)) * k5))));
      f32x2 k6 = feval(tb + dt, pk_fma(dtv, a6, S));
      f32x2 fin = pk_fma(bc(F(35,384)), k1,
                  pk_fma(bc(F(500,1113)), k3,
                  pk_fma(bc(F(125,192)), k4,
                  pk_fma(bc(-F(2187,6784)), k5, bc(F(11,84)) * k6))));
      S = pk_fma(dtv, fin, S);
    }
    if (lane < 16) *(float2*)&out[(s * TT + iv + 1) * 2] = make_float2(S.x, S.y);
  }
}

extern "C" void kernel_launch(void* const* d_in, const int* in_sizes, int n_in,
                              void* d_out, int out_size, void* d_ws, size_t ws_size,
                              hipStream_t stream) {
  const float* r0 = (const float*)d_in[0];
  const float* t  = (const float*)d_in[1];
  const float* W1 = (const float*)d_in[2];
  const float* b1 = (const float*)d_in[3];
  const float* W2 = (const float*)d_in[4];
  const float* b2 = (const float*)d_in[5];
  const float* W3 = (const float*)d_in[6];
  const float* b3 = (const float*)d_in[7];
  float* out = (float*)d_out;
  const int B = in_sizes[0] / 2;        // 16384
  dim3 grid(B / 16), block(64);         // 1024 blocks x 64 threads (1 wave)
  node_kernel<<<grid, block, 0, stream>>>(r0, t, W1, b1, W2, b2, W3, b3, out);
}

// Round 7
// 191.752 us; speedup vs baseline: 4.1823x; 1.0197x over previous
//
#include <hip/hip_runtime.h>

// AugmentedNeuralODE, round 7: R6's in-lane B-frag trick + 4-way weight shard.
// R6 failed on register spills (45 MB/dispatch scratch traffic, 1 wave/SIMD).
// Now: 1024 blocks x 256 threads; 4 waves share the SAME 16 samples.
//   L1: lane (w,quad,m16) computes slab g=w*4+quad (units k=g*8+j) for sample
//       m16 -> 1 ds_write_b128; B-frags read back as 4 ds_read_b128 (slab
//       kk*4+quad). In-lane pack, no transpose.
//   L2: wave w owns out-tiles {2w,2w+1}: W2 frags = 32 VGPR, 8 MFMA/eval.
//   epi: 4 tanh-pairs + W3 partials, shfl-xor quad reduce, vpS exchange.
// ~150 VGPR -> 2 waves/SIMD: second wave hides trans/MFMA/DS latency.
// Math bit-identical to R6 (same tanh_pre, K-order, bf16 rounding).

#define HID 128
#define TT  8
#define F(a,b) ((float)((double)(a)/(double)(b)))
#define K2C 2.8853900817779268f   // 2*log2(e), folded into W1/b1/W2/b2

typedef __attribute__((ext_vector_type(8))) short bf16x8;
typedef __attribute__((ext_vector_type(4))) float f32x4;
typedef __attribute__((ext_vector_type(2))) float f32x2;

union Frag { bf16x8 v; unsigned short u[8]; unsigned int d[4]; };

__device__ __forceinline__ f32x2 bc(float s) { return f32x2{s, s}; }
__device__ __forceinline__ f32x2 pk_fma(f32x2 a, f32x2 b, f32x2 c) {
#if __has_builtin(__builtin_elementwise_fma)
  return __builtin_elementwise_fma(a, b, c);
#else
  return a * b + c;
#endif
}
__device__ __forceinline__ float exp2_fast(float x) {
#if __has_builtin(__builtin_amdgcn_exp2f)
  return __builtin_amdgcn_exp2f(x);
#else
  return __builtin_exp2f(x);
#endif
}
__device__ __forceinline__ unsigned short f2bf(float f) {
  unsigned u = __builtin_bit_cast(unsigned, f);
  u += 0x7FFFu + ((u >> 16) & 1u);          // RNE
  return (unsigned short)(u >> 16);
}
__device__ __forceinline__ unsigned pack2bf(float a, float b) {
  unsigned ua = __builtin_bit_cast(unsigned, a);
  unsigned ub = __builtin_bit_cast(unsigned, b);
  ua += 0x7FFFu + ((ua >> 16) & 1u);
  ub += 0x7FFFu + ((ub >> 16) & 1u);
  return __builtin_amdgcn_perm(ub, ua, 0x07060302u);
}
// u pre-scaled by 2*log2(e): tanh(x) = 1 - 2/(exp2(u)+1)
__device__ __forceinline__ f32x2 tanh_pre(f32x2 u) {
  f32x2 e;
  e.x = exp2_fast(u.x);
  e.y = exp2_fast(u.y);
  f32x2 d = e + bc(1.0f);
  f32x2 r;
  r.x = __builtin_amdgcn_rcpf(d.x);
  r.y = __builtin_amdgcn_rcpf(d.y);
  return pk_fma(bc(-2.0f), r, bc(1.0f));
}

__global__ __launch_bounds__(256, 2) void node_kernel(
    const float* __restrict__ r0, const float* __restrict__ tarr,
    const float* __restrict__ W1, const float* __restrict__ b1,
    const float* __restrict__ W2, const float* __restrict__ b2,
    const float* __restrict__ W3, const float* __restrict__ b3,
    float* __restrict__ out)
{
  __shared__ uint4  h1L[16][16];   // [slab g][sample], 16B = 8 bf16; 4 KB
  __shared__ float2 vpS[16][4];    // [sample][wave] partial velocities; 512 B

  const int tid  = (int)threadIdx.x;
  const int lane = tid & 63;
  const int w    = __builtin_amdgcn_readfirstlane(tid >> 6); // wave 0..3
  const int quad = lane >> 4;          // 0..3
  const int m16  = lane & 15;          // my sample (column)
  const int g    = w * 4 + quad;       // my L1 slab (8 units)
  const int s    = (int)blockIdx.x * 16 + m16;

  // ---- one-time preloads, K2-folded ----
  // L1 weights for my 8 units k = g*8 + j (4 pairs)
  f32x2 w1x[4], w1y[4], w1t[4], bb1[4];
  #pragma unroll
  for (int p = 0; p < 4; ++p) {
    int i = g * 8 + 2 * p;
    w1x[p] = f32x2{W1[0 * HID + i], W1[0 * HID + i + 1]} * bc(K2C);
    w1y[p] = f32x2{W1[1 * HID + i], W1[1 * HID + i + 1]} * bc(K2C);
    w1t[p] = f32x2{W1[4 * HID + i], W1[4 * HID + i + 1]} * bc(K2C);
    bb1[p] = f32x2{b1[i], b1[i + 1]} * bc(K2C);
  }
  // W2 A-frags for my 2 out-tiles: A[m16][k=kk*32+quad*8+j] = W2[k][o]
  Frag W2f[2][4];
  #pragma unroll
  for (int oti = 0; oti < 2; ++oti) {
    int o = (2 * w + oti) * 16 + m16;
    #pragma unroll
    for (int kk = 0; kk < 4; ++kk)
      #pragma unroll
      for (int j = 0; j < 8; ++j)
        W2f[oti][kk].u[j] = f2bf(W2[(kk * 32 + quad * 8 + j) * HID + o] * K2C);
  }
  // acc-init = b2*K2; C rows this lane holds: o = (2w+oti)*16 + quad*4 + rr
  f32x4 b2i[2];
  f32x2 w3v[2][4];
  #pragma unroll
  for (int oti = 0; oti < 2; ++oti)
    #pragma unroll
    for (int rr = 0; rr < 4; ++rr) {
      int o = (2 * w + oti) * 16 + quad * 4 + rr;
      b2i[oti][rr] = b2[o] * K2C;
      w3v[oti][rr] = f32x2{W3[o * 2 + 0], W3[o * 2 + 1]};
    }
  const f32x2 b3v = f32x2{b3[0], b3[1]};

  f32x2 S = f32x2{r0[2 * s + 0], r0[2 * s + 1]};
  if (tid < 16) *(float2*)&out[(s * TT + 0) * 2] = make_float2(S.x, S.y);

  auto feval = [&](float tt, f32x2 st) -> f32x2 {
    const f32x2 sx = bc(st.x), sy = bc(st.y), tv = bc(tt);
    // ---- layer 1: my 8 units -> bf16 -> my slab ----
    {
      unsigned pd[4];
      #pragma unroll
      for (int p = 0; p < 4; ++p) {
        f32x2 a = pk_fma(sx, w1x[p], bb1[p]);
        a = pk_fma(sy, w1y[p], a);
        a = pk_fma(tv, w1t[p], a);
        f32x2 h = tanh_pre(a);
        pd[p] = pack2bf(h.x, h.y);
      }
      h1L[g][m16] = make_uint4(pd[0], pd[1], pd[2], pd[3]);
    }
    __syncthreads();
    // ---- layer 2: 8 MFMA (2 tiles x 4 K-slabs), acc pre-init b2 ----
    f32x4 acc[2];
    acc[0] = b2i[0]; acc[1] = b2i[1];
    #pragma unroll
    for (int kk = 0; kk < 4; ++kk) {
      Frag bv;
      uint4 t4 = h1L[kk * 4 + quad][m16];
      bv.d[0] = t4.x; bv.d[1] = t4.y; bv.d[2] = t4.z; bv.d[3] = t4.w;
      acc[0] = __builtin_amdgcn_mfma_f32_16x16x32_bf16(W2f[0][kk].v, bv.v, acc[0], 0, 0, 0);
      acc[1] = __builtin_amdgcn_mfma_f32_16x16x32_bf16(W2f[1][kk].v, bv.v, acc[1], 0, 0, 0);
    }
    // ---- h2 tanh + W3 partials (C: row = quad*4+rr, col = m16) ----
    f32x2 vs = bc(0.f);
    #pragma unroll
    for (int oti = 0; oti < 2; ++oti)
      #pragma unroll
      for (int p = 0; p < 2; ++p) {
        f32x2 av = f32x2{acc[oti][2 * p], acc[oti][2 * p + 1]};
        f32x2 h2 = tanh_pre(av);
        vs = pk_fma(bc(h2.x), w3v[oti][2 * p + 0], vs);
        vs = pk_fma(bc(h2.y), w3v[oti][2 * p + 1], vs);
      }
    // cross-quad reduce, then cross-wave via LDS
    float px = vs.x, py = vs.y;
    px += __shfl_xor(px, 16); px += __shfl_xor(px, 32);
    py += __shfl_xor(py, 16); py += __shfl_xor(py, 32);
    if (lane < 16) vpS[m16][w] = make_float2(px, py);
    __syncthreads();
    float4 q0 = *(const float4*)&vpS[m16][0];   // waves 0,1
    float4 q1 = *(const float4*)&vpS[m16][2];   // waves 2,3
    f32x2 rv = b3v + f32x2{q0.x, q0.y} + f32x2{q0.z, q0.w}
                   + f32x2{q1.x, q1.y} + f32x2{q1.z, q1.w};
    return rv;
  };

  #pragma unroll 1
  for (int iv = 0; iv < TT - 1; ++iv) {
    float t0 = tarr[iv], t1 = tarr[iv + 1];
    float dt = (t1 - t0) * 0.5f;
    #pragma unroll 1
    for (int ss = 0; ss < 2; ++ss) {
      float tb = (ss == 0) ? t0 : (t0 + dt);
      const f32x2 dtv = bc(dt);
      f32x2 k1 = feval(tb, S);
      f32x2 k2 = feval(tb + dt * F(1,5), pk_fma(bc(dt * F(1,5)), k1, S));
      f32x2 a3 = pk_fma(bc(F(9,40)), k2, bc(F(3,40)) * k1);
      f32x2 k3 = feval(tb + dt * F(3,10), pk_fma(dtv, a3, S));
      f32x2 a4 = pk_fma(bc(F(44,45)), k1,
                 pk_fma(bc(-F(56,15)), k2, bc(F(32,9)) * k3));
      f32x2 k4 = feval(tb + dt * F(4,5), pk_fma(dtv, a4, S));
      f32x2 a5 = pk_fma(bc(F(19372,6561)), k1,
                 pk_fma(bc(-F(25360,2187)), k2,
                 pk_fma(bc(F(64448,6561)), k3, bc(-F(212,729)) * k4)));
      f32x2 k5 = feval(tb + dt * F(8,9), pk_fma(dtv, a5, S));
      f32x2 a6 = pk_fma(bc(F(9017,3168)), k1,
                 pk_fma(bc(-F(355,33)), k2,
                 pk_fma(bc(F(46732,5247)), k3,
                 pk_fma(bc(F(49,176)), k4, bc(-F(5103,18656)) * k5))));
      f32x2 k6 = feval(tb + dt, pk_fma(dtv, a6, S));
      f32x2 fin = pk_fma(bc(F(35,384)), k1,
                  pk_fma(bc(F(500,1113)), k3,
                  pk_fma(bc(F(125,192)), k4,
                  pk_fma(bc(-F(2187,6784)), k5, bc(F(11,84)) * k6))));
      S = pk_fma(dtv, fin, S);
    }
    if (tid < 16) *(float2*)&out[(s * TT + iv + 1) * 2] = make_float2(S.x, S.y);
  }
}

extern "C" void kernel_launch(void* const* d_in, const int* in_sizes, int n_in,
                              void* d_out, int out_size, void* d_ws, size_t ws_size,
                              hipStream_t stream) {
  const float* r0 = (const float*)d_in[0];
  const float* t  = (const float*)d_in[1];
  const float* W1 = (const float*)d_in[2];
  const float* b1 = (const float*)d_in[3];
  const float* W2 = (const float*)d_in[4];
  const float* b2 = (const float*)d_in[5];
  const float* W3 = (const float*)d_in[6];
  const float* b3 = (const float*)d_in[7];
  float* out = (float*)d_out;
  const int B = in_sizes[0] / 2;        // 16384
  dim3 grid(B / 16), block(256);        // 1024 blocks x 256 threads (4 waves)
  node_kernel<<<grid, block, 0, stream>>>(r0, t, W1, b1, W2, b2, W3, b3, out);
}

// Round 8
// 182.086 us; speedup vs baseline: 4.4043x; 1.0531x over previous
//
#include <hip/hip_runtime.h>

// AugmentedNeuralODE, round 8: R6 (wave-autonomous, LDS-free) + AGPR pinning.
// R3-R7 were LDS-pipe-bound (~114 DS-cyc/wave-eval ~= 127us ~= wall). R6
// removed LDS but scratch-spilled (430 regs > 256 arch cap -> 45 MB HBM
// scratch traffic). Fix: park W2 bf16 A-frags (128 regs) and b2 acc-init
// (32 regs) in the AGPR file via asm "+a" pins -- MFMA reads A and C from
// AGPR natively, so the pins cost one copy at startup and zero per eval.
// Arch VGPRs: W1 (128) + W3 (64) + state/temps (~50) <= 256, no spill.
// L1 tanh for K-slab kk is interleaved with slab kk-1's MFMAs.
// 1024 blocks x 64 threads, 1 wave/SIMD, no __shared__, no __syncthreads.
// Math bit-identical to R6/R7 (absmax should repeat 0.03125).

#define HID 128
#define TT  8
#define F(a,b) ((float)((double)(a)/(double)(b)))
#define K2C 2.8853900817779268f   // 2*log2(e), folded into W1/b1/W2/b2

typedef __attribute__((ext_vector_type(8))) short bf16x8;
typedef __attribute__((ext_vector_type(4))) float f32x4;
typedef __attribute__((ext_vector_type(2))) float f32x2;

union Frag { bf16x8 v; unsigned short u[8]; unsigned int d[4]; };

__device__ __forceinline__ f32x2 bc(float s) { return f32x2{s, s}; }
__device__ __forceinline__ f32x2 pk_fma(f32x2 a, f32x2 b, f32x2 c) {
#if __has_builtin(__builtin_elementwise_fma)
  return __builtin_elementwise_fma(a, b, c);
#else
  return a * b + c;
#endif
}
__device__ __forceinline__ float exp2_fast(float x) {
#if __has_builtin(__builtin_amdgcn_exp2f)
  return __builtin_amdgcn_exp2f(x);
#else
  return __builtin_exp2f(x);
#endif
}
__device__ __forceinline__ unsigned short f2bf(float f) {
  unsigned u = __builtin_bit_cast(unsigned, f);
  u += 0x7FFFu + ((u >> 16) & 1u);          // RNE
  return (unsigned short)(u >> 16);
}
__device__ __forceinline__ unsigned pack2bf(float a, float b) {
  unsigned ua = __builtin_bit_cast(unsigned, a);
  unsigned ub = __builtin_bit_cast(unsigned, b);
  ua += 0x7FFFu + ((ua >> 16) & 1u);
  ub += 0x7FFFu + ((ub >> 16) & 1u);
  return __builtin_amdgcn_perm(ub, ua, 0x07060302u);
}
// u pre-scaled by 2*log2(e): tanh(x) = 1 - 2/(exp2(u)+1)
__device__ __forceinline__ f32x2 tanh_pre(f32x2 u) {
  f32x2 e;
  e.x = exp2_fast(u.x);
  e.y = exp2_fast(u.y);
  f32x2 d = e + bc(1.0f);
  f32x2 r;
  r.x = __builtin_amdgcn_rcpf(d.x);
  r.y = __builtin_amdgcn_rcpf(d.y);
  return pk_fma(bc(-2.0f), r, bc(1.0f));
}

__global__ __launch_bounds__(64, 1) void node_kernel(
    const float* __restrict__ r0, const float* __restrict__ tarr,
    const float* __restrict__ W1, const float* __restrict__ b1,
    const float* __restrict__ W2, const float* __restrict__ b2,
    const float* __restrict__ W3, const float* __restrict__ b3,
    float* __restrict__ out)
{
  const int lane = (int)(threadIdx.x & 63u);
  const int quad = lane >> 4;          // 0..3
  const int m16  = lane & 15;          // my sample (column)
  const int s    = (int)blockIdx.x * 16 + m16;

  // ---- one-time preloads, all K2-folded ----
  // W1 for my 32 units k = kk*32 + quad*8 + j (16 pairs) -- arch VGPRs (128)
  f32x2 w1x[16], w1y[16], w1t[16], bb1[16];
  #pragma unroll
  for (int kk = 0; kk < 4; ++kk)
    #pragma unroll
    for (int p = 0; p < 4; ++p) {
      int i = kk * 32 + quad * 8 + 2 * p;
      int idx = kk * 4 + p;
      w1x[idx] = f32x2{W1[0 * HID + i], W1[0 * HID + i + 1]} * bc(K2C);
      w1y[idx] = f32x2{W1[1 * HID + i], W1[1 * HID + i + 1]} * bc(K2C);
      w1t[idx] = f32x2{W1[4 * HID + i], W1[4 * HID + i + 1]} * bc(K2C);
      bb1[idx] = f32x2{b1[i], b1[i + 1]} * bc(K2C);
    }
  // W2 A-frags for ALL 8 out-tiles -> pinned into AGPRs (128 regs)
  Frag W2f[8][4];
  #pragma unroll
  for (int t = 0; t < 8; ++t) {
    int o = t * 16 + m16;
    #pragma unroll
    for (int kk = 0; kk < 4; ++kk) {
      #pragma unroll
      for (int j = 0; j < 8; ++j)
        W2f[t][kk].u[j] = f2bf(W2[(kk * 32 + quad * 8 + j) * HID + o] * K2C);
      asm volatile("" : "+a"(W2f[t][kk].v));   // park in AGPR (MFMA A-src)
    }
  }
  // acc-init = b2*K2 -> pinned into AGPRs (32 regs, MFMA C-src)
  f32x4 b2i[8];
  f32x2 w3v[8][4];                      // W3 stays in arch (64 regs)
  #pragma unroll
  for (int t = 0; t < 8; ++t) {
    #pragma unroll
    for (int rr = 0; rr < 4; ++rr) {
      int o = t * 16 + quad * 4 + rr;
      b2i[t][rr] = b2[o] * K2C;
      w3v[t][rr] = f32x2{W3[o * 2 + 0], W3[o * 2 + 1]};
    }
    asm volatile("" : "+a"(b2i[t]));
  }
  const f32x2 b3v = f32x2{b3[0], b3[1]};

  f32x2 S = f32x2{r0[2 * s + 0], r0[2 * s + 1]};
  if (lane < 16) *(float2*)&out[(s * TT + 0) * 2] = make_float2(S.x, S.y);

  auto feval = [&](float tt, f32x2 st) -> f32x2 {
    const f32x2 sx = bc(st.x), sy = bc(st.y), tv = bc(tt);
    // ---- interleaved: per K-slab, 4 tanh-pairs -> B-frag -> 8 MFMAs ----
    f32x4 acc[8];
    #pragma unroll
    for (int kk = 0; kk < 4; ++kk) {
      unsigned pd[4];
      #pragma unroll
      for (int p = 0; p < 4; ++p) {
        int idx = kk * 4 + p;
        f32x2 a = pk_fma(sx, w1x[idx], bb1[idx]);
        a = pk_fma(sy, w1y[idx], a);
        a = pk_fma(tv, w1t[idx], a);
        f32x2 h = tanh_pre(a);
        pd[p] = pack2bf(h.x, h.y);
      }
      Frag bv;
      bv.d[0] = pd[0]; bv.d[1] = pd[1]; bv.d[2] = pd[2]; bv.d[3] = pd[3];
      if (kk == 0) {
        #pragma unroll
        for (int t = 0; t < 8; ++t)
          acc[t] = __builtin_amdgcn_mfma_f32_16x16x32_bf16(
              W2f[t][0].v, bv.v, b2i[t], 0, 0, 0);
      } else {
        #pragma unroll
        for (int t = 0; t < 8; ++t)
          acc[t] = __builtin_amdgcn_mfma_f32_16x16x32_bf16(
              W2f[t][kk].v, bv.v, acc[t], 0, 0, 0);
      }
    }
    // ---- h2 tanh + layer-3 partials (C: row = quad*4+rr, col = m16) ----
    f32x2 vs = bc(0.f);
    #pragma unroll
    for (int t = 0; t < 8; ++t)
      #pragma unroll
      for (int p = 0; p < 2; ++p) {
        f32x2 av = f32x2{acc[t][2 * p], acc[t][2 * p + 1]};
        f32x2 h2 = tanh_pre(av);
        vs = pk_fma(bc(h2.x), w3v[t][2 * p + 0], vs);
        vs = pk_fma(bc(h2.y), w3v[t][2 * p + 1], vs);
      }
    // cross-quad reduce (sample m16 partials live at lanes m16+16q)
    float px = vs.x, py = vs.y;
    px += __shfl_xor(px, 16); px += __shfl_xor(px, 32);
    py += __shfl_xor(py, 16); py += __shfl_xor(py, 32);
    return f32x2{px, py} + b3v;
  };

  #pragma unroll 1
  for (int iv = 0; iv < TT - 1; ++iv) {
    float t0 = tarr[iv], t1 = tarr[iv + 1];
    float dt = (t1 - t0) * 0.5f;
    #pragma unroll 1
    for (int ss = 0; ss < 2; ++ss) {
      float tb = (ss == 0) ? t0 : (t0 + dt);
      const f32x2 dtv = bc(dt);
      f32x2 k1 = feval(tb, S);
      f32x2 k2 = feval(tb + dt * F(1,5), pk_fma(bc(dt * F(1,5)), k1, S));
      f32x2 a3 = pk_fma(bc(F(9,40)), k2, bc(F(3,40)) * k1);
      f32x2 k3 = feval(tb + dt * F(3,10), pk_fma(dtv, a3, S));
      f32x2 a4 = pk_fma(bc(F(44,45)), k1,
                 pk_fma(bc(-F(56,15)), k2, bc(F(32,9)) * k3));
      f32x2 k4 = feval(tb + dt * F(4,5), pk_fma(dtv, a4, S));
      f32x2 a5 = pk_fma(bc(F(19372,6561)), k1,
                 pk_fma(bc(-F(25360,2187)), k2,
                 pk_fma(bc(F(64448,6561)), k3, bc(-F(212,729)) * k4)));
      f32x2 k5 = feval(tb + dt * F(8,9), pk_fma(dtv, a5, S));
      f32x2 a6 = pk_fma(bc(F(9017,3168)), k1,
                 pk_fma(bc(-F(355,33)), k2,
                 pk_fma(bc(F(46732,5247)), k3,
                 pk_fma(bc(F(49,176)), k4, bc(-F(5103,18656)) * k5))));
      f32x2 k6 = feval(tb + dt, pk_fma(dtv, a6, S));
      f32x2 fin = pk_fma(bc(F(35,384)), k1,
                  pk_fma(bc(F(500,1113)), k3,
                  pk_fma(bc(F(125,192)), k4,
                  pk_fma(bc(-F(2187,6784)), k5, bc(F(11,84)) * k6))));
      S = pk_fma(dtv, fin, S);
    }
    if (lane < 16) *(float2*)&out[(s * TT + iv + 1) * 2] = make_float2(S.x, S.y);
  }
}

extern "C" void kernel_launch(void* const* d_in, const int* in_sizes, int n_in,
                              void* d_out, int out_size, void* d_ws, size_t ws_size,
                              hipStream_t stream) {
  const float* r0 = (const float*)d_in[0];
  const float* t  = (const float*)d_in[1];
  const float* W1 = (const float*)d_in[2];
  const float* b1 = (const float*)d_in[3];
  const float* W2 = (const float*)d_in[4];
  const float* b2 = (const float*)d_in[5];
  const float* W3 = (const float*)d_in[6];
  const float* b3 = (const float*)d_in[7];
  float* out = (float*)d_out;
  const int B = in_sizes[0] / 2;        // 16384
  dim3 grid(B / 16), block(64);         // 1024 blocks x 64 threads (1 wave)
  node_kernel<<<grid, block, 0, stream>>>(r0, t, W1, b1, W2, b2, W3, b3, out);
}